// Round 1
// 781.331 us; speedup vs baseline: 1.4918x; 1.4918x over previous
//
#include <hip/hip_runtime.h>
#include <hip/hip_bf16.h>

// FFT-based causal long convolution for (b=4, l=8192, d=1024) fp32.
// One workgroup per (b, d) pair. Real FFT of N=16384 done as complex FFT of
// M=8192 via even/odd packing; 64 KB LDS holds the whole sequence.
//
// vs previous version:
//  - Radix-2^2 fused passes: two radix-2 stages per LDS round-trip (13 -> 7
//    passes per FFT), one sincos per 4-point group (wA, -i*wA, wB=wA^2).
//    Stage sequence/ordering identical to pure radix-2 => rev13 unpack intact.
//  - LDS XOR bank swizzle sigma(e) = e ^ ((e>>4)&15) ^ ((e>>8)&15): every
//    access pattern (contiguous, stride-2^k butterflies, bit-reversed phase C)
//    lands at the ds_read_b64 conflict-free baseline.
//  - Bijective XCD-aware block swizzle: each XCD gets a contiguous d-range so
//    strided 4B/4KB x-reads / y-writes merge into full lines in its L2.
//  - Filter FFT precomputed once per d (not once per (b,d)) into workspace
//    (K[k], K[M-k] as float4), guarded by ws_size with in-kernel fallback.

#define M 8192            // complex FFT size
#define LOGM 13
#define NTH 256
#define MAXP 17           // ceil((M/2+1)/NTH)

__device__ __forceinline__ float2 cadd(float2 a, float2 b){ return make_float2(a.x+b.x, a.y+b.y); }
__device__ __forceinline__ float2 csub(float2 a, float2 b){ return make_float2(a.x-b.x, a.y-b.y); }
__device__ __forceinline__ float2 cmul(float2 a, float2 b){ return make_float2(a.x*b.x - a.y*b.y, a.x*b.y + a.y*b.x); }
__device__ __forceinline__ float2 conjf2(float2 a){ return make_float2(a.x, -a.y); }

__device__ __forceinline__ int rev13(int k){ return (int)(__brev((unsigned)k) >> 19); }

// LDS bank-conflict swizzle: bijective, identity on bits >=4.
__device__ __forceinline__ int swz(int e){ return e ^ ((e >> 4) & 15) ^ ((e >> 8) & 15); }

static __device__ const float PI_F = 3.14159265358979323846f;

// Forward radix-2 DIF, radix-2^2 fused: natural-order input, bit-reversed output.
// Halves: {4096,2048},{1024,512},{256,128},{64,32},{16,8},{4,2} fused + single {1}.
__device__ __forceinline__ void fft_dif_fused(float2* L, int tid) {
  for (int h = M/2; h >= 4; h >>= 2) {
    const int hh = h >> 1;
    const float astep = -PI_F / (float)h;
    for (int idx = tid; idx < M/4; idx += NTH) {
      int j  = idx & (hh - 1);
      int base = ((idx - j) << 2) + j;        // (idx>>log2(hh)) * 2h + j
      int i0 = base, i1 = base + hh, i2 = base + h, i3 = base + h + hh;
      float s, c;
      __sincosf((float)j * astep, &s, &c);
      float2 wA = make_float2(c, s);           // e^{-i*pi*j/h}
      float2 wB = cmul(wA, wA);                // e^{-i*pi*j/(h/2)}
      float2 a = L[swz(i0)], b = L[swz(i1)], cc = L[swz(i2)], d = L[swz(i3)];
      // stage half=h: pairs (a,cc) w=wA ; (b,d) w=-i*wA
      float2 ac0 = cadd(a, cc);
      float2 ac1 = cmul(csub(a, cc), wA);
      float2 bd0 = cadd(b, d);
      float2 tbd = csub(b, d);
      float2 bd1 = cmul(tbd, make_float2(wA.y, -wA.x));   // (b-d) * (-i*wA)
      // stage half=h/2: pairs (ac0,bd0) and (ac1,bd1), twiddle wB
      L[swz(i0)] = cadd(ac0, bd0);
      L[swz(i1)] = cmul(csub(ac0, bd0), wB);
      L[swz(i2)] = cadd(ac1, bd1);
      L[swz(i3)] = cmul(csub(ac1, bd1), wB);
    }
    __syncthreads();
  }
  // final half=1 stage (twiddle = 1)
  for (int idx = tid; idx < M/2; idx += NTH) {
    int i0 = 2*idx, i1 = i0 + 1;
    float2 a = L[swz(i0)], b = L[swz(i1)];
    L[swz(i0)] = cadd(a, b);
    L[swz(i1)] = csub(a, b);
  }
  __syncthreads();
}

// Inverse radix-2 DIT, radix-2^2 fused: bit-reversed input, natural output.
// Unscaled (no 1/M). Single {1} + fused {2,4},{8,16},...,{2048,4096}.
__device__ __forceinline__ void fft_dit_inv_fused(float2* L, int tid) {
  for (int idx = tid; idx < M/2; idx += NTH) {
    int i0 = 2*idx, i1 = i0 + 1;
    float2 a = L[swz(i0)], b = L[swz(i1)];
    L[swz(i0)] = cadd(a, b);
    L[swz(i1)] = csub(a, b);
  }
  __syncthreads();
  for (int h = 4; h <= M/2; h <<= 2) {
    const int hh = h >> 1;
    const float astep = PI_F / (float)h;
    for (int idx = tid; idx < M/4; idx += NTH) {
      int j  = idx & (hh - 1);
      int base = ((idx - j) << 2) + j;
      int i0 = base, i1 = base + hh, i2 = base + h, i3 = base + h + hh;
      float s, c;
      __sincosf((float)j * astep, &s, &c);
      float2 wA = make_float2(c, s);           // e^{+i*pi*j/h}
      float2 wB = cmul(wA, wA);                // e^{+i*pi*j/(h/2)}
      float2 a = L[swz(i0)], b = L[swz(i1)], cc = L[swz(i2)], d = L[swz(i3)];
      // stage half=h/2: pairs (a,b) and (cc,d), twiddle wB
      float2 t  = cmul(b, wB);
      float2 a1 = cadd(a, t), b1 = csub(a, t);
      float2 u  = cmul(d, wB);
      float2 c1 = cadd(cc, u), d1 = csub(cc, u);
      // stage half=h: pairs (a1,c1) w=wA ; (b1,d1) w=+i*wA
      float2 v = cmul(c1, wA);
      L[swz(i0)] = cadd(a1, v);
      L[swz(i2)] = csub(a1, v);
      float2 w2 = cmul(d1, make_float2(-wA.y, wA.x));     // d1 * (i*wA)
      L[swz(i1)] = cadd(b1, w2);
      L[swz(i3)] = csub(b1, w2);
    }
    __syncthreads();
  }
}

// Precompute per-d filter spectrum: (K[k], K[M-k]) for k=0..M/2 as float4.
__global__ __launch_bounds__(NTH, 2)
void filt_fft_kernel(const float* __restrict__ filt, float4* __restrict__ kf) {
  __shared__ float2 L[M];
  const int tid = threadIdx.x;
  const int d = blockIdx.x;
  const float* fp = filt + (size_t)d * 8192;
  for (int m = tid; m < M; m += NTH) {
    float2 v = make_float2(0.f, 0.f);
    if (m < M/2) { v.x = fp[2*m]; v.y = fp[2*m + 1]; }
    L[swz(m)] = v;
  }
  __syncthreads();
  fft_dif_fused(L, tid);
  float4* out = kf + (size_t)d * (M/2 + 1);
  for (int k = tid; k <= M/2; k += NTH) {
    int rk  = rev13(k);
    int rmk = rev13((M - k) & (M - 1));
    float2 Zk = L[swz(rk)], Zmk = L[swz(rmk)];
    float2 Ze = make_float2(0.5f*(Zk.x + Zmk.x), 0.5f*(Zk.y - Zmk.y));
    float2 t  = make_float2(Zk.x - Zmk.x, Zk.y + Zmk.y);
    float2 Zo = make_float2(0.5f*t.y, -0.5f*t.x);
    float s, c; __sincosf(-PI_F * (float)k * (1.0f/(float)M), &s, &c);
    float2 W = make_float2(c, s);
    float2 WZo = cmul(W, Zo);
    float2 Kk = cadd(Ze, WZo);
    float2 Km = conjf2(csub(Ze, WZo));
    out[k] = make_float4(Kk.x, Kk.y, Km.x, Km.y);
  }
}

__global__ __launch_bounds__(NTH, 2)
void longconv_fft_kernel(const float* __restrict__ x,
                         const float* __restrict__ filt,
                         const float4* __restrict__ kf,   // may be null -> compute in-kernel
                         float* __restrict__ y,
                         int B) {
  __shared__ float2 L[M];                    // 64 KB
  const int tid = threadIdx.x;

  // Bijective XCD-aware swizzle: XCD j owns a contiguous 512-block chunk,
  // so co-resident blocks on one XCD cover consecutive d -> L2 line merge.
  const int nwg  = gridDim.x;                // 4096, multiple of 8
  const int cpx  = nwg >> 3;
  const int bid  = blockIdx.x;
  const int blk  = (bid & 7) * cpx + (bid >> 3);
  const int d = blk & 1023;
  const int b = blk >> 10;

  float2 Kk[MAXP], Kmk[MAXP];

  // ---------------- Phase A: filter FFT (fallback only) ----------------
  if (kf == nullptr) {
    const float* fp = filt + (size_t)d * 8192;
    for (int m = tid; m < M; m += NTH) {
      float2 v = make_float2(0.f, 0.f);
      if (m < M/2) { v.x = fp[2*m]; v.y = fp[2*m + 1]; }
      L[swz(m)] = v;
    }
    __syncthreads();
    fft_dif_fused(L, tid);
#pragma unroll
    for (int p = 0; p < MAXP; ++p) {
      int k = tid + p * NTH;
      if (k <= M/2) {
        int rk  = rev13(k);
        int rmk = rev13((M - k) & (M - 1));
        float2 Zk = L[swz(rk)], Zmk = L[swz(rmk)];
        float2 Ze = make_float2(0.5f*(Zk.x + Zmk.x), 0.5f*(Zk.y - Zmk.y));
        float2 t  = make_float2(Zk.x - Zmk.x, Zk.y + Zmk.y);
        float2 Zo = make_float2(0.5f*t.y, -0.5f*t.x);
        float s, c; __sincosf(-PI_F * (float)k * (1.0f/(float)M), &s, &c);
        float2 W = make_float2(c, s);
        float2 WZo = cmul(W, Zo);
        Kk[p]  = cadd(Ze, WZo);
        Kmk[p] = conjf2(csub(Ze, WZo));
      }
    }
    __syncthreads();                          // all reads of L done before reuse
  }

  // ---------------- Phase B: signal FFT ----------------
  const float* xp = x + (size_t)b * 8192 * 1024 + d;
  for (int m = tid; m < M; m += NTH) {
    float2 v = make_float2(0.f, 0.f);
    if (m < M/2) {
      v.x = xp[(size_t)(2*m)     * 1024];
      v.y = xp[(size_t)(2*m + 1) * 1024];
    }
    L[swz(m)] = v;
  }
  __syncthreads();
  fft_dif_fused(L, tid);

  // ---------------- Phase C: unpack * K, repack (in place, pairwise) ----------------
  const float4* kfp = (kf != nullptr) ? (kf + (size_t)d * (M/2 + 1)) : nullptr;
#pragma unroll
  for (int p = 0; p < MAXP; ++p) {
    int k = tid + p * NTH;
    if (k <= M/2) {
      float2 Kkv, Kmv;
      if (kfp != nullptr) {
        float4 kv = kfp[k];
        Kkv = make_float2(kv.x, kv.y);
        Kmv = make_float2(kv.z, kv.w);
      } else {
        Kkv = Kk[p];
        Kmv = Kmk[p];
      }
      int rk  = rev13(k);
      int rmk = rev13((M - k) & (M - 1));
      float2 Zk = L[swz(rk)], Zmk = L[swz(rmk)];
      float2 Ze = make_float2(0.5f*(Zk.x + Zmk.x), 0.5f*(Zk.y - Zmk.y));
      float2 t  = make_float2(Zk.x - Zmk.x, Zk.y + Zmk.y);
      float2 Zo = make_float2(0.5f*t.y, -0.5f*t.x);
      float s, c; __sincosf(-PI_F * (float)k * (1.0f/(float)M), &s, &c);
      float2 W = make_float2(c, s);
      float2 WZo = cmul(W, Zo);
      float2 Uk  = cadd(Ze, WZo);             // U[k]
      float2 Umk = conjf2(csub(Ze, WZo));     // U[M-k]
      float2 Yk  = cmul(Uk,  Kkv);
      float2 Ymk = cmul(Umk, Kmv);
      // Repack Y (rfft spectrum) into packed-complex spectrum Zy:
      float2 Ye  = make_float2(0.5f*(Yk.x + Ymk.x), 0.5f*(Yk.y - Ymk.y));
      float2 t2  = make_float2(0.5f*(Yk.x - Ymk.x), 0.5f*(Yk.y + Ymk.y));
      float2 Zoy = cmul(conjf2(W), t2);
      float2 Zyk  = make_float2(Ye.x - Zoy.y, Ye.y + Zoy.x);
      float2 Zymk = make_float2(Ye.x + Zoy.y, Zoy.x - Ye.y);
      L[swz(rk)]  = Zyk;
      L[swz(rmk)] = Zymk;                     // k==0 / k==M/2: same slot, same value
    }
  }
  __syncthreads();

  // ---------------- Phase D: inverse FFT ----------------
  fft_dit_inv_fused(L, tid);

  // ---------------- Phase E: write first l=8192 samples, scaled by 1/M ----------------
  float* yp = y + (size_t)b * 8192 * 1024 + d;
  const float inv = 1.0f / (float)M;
  for (int m = tid; m < M/2; m += NTH) {
    float2 v = L[swz(m)];
    yp[(size_t)(2*m)     * 1024] = v.x * inv;
    yp[(size_t)(2*m + 1) * 1024] = v.y * inv;
  }
}

extern "C" void kernel_launch(void* const* d_in, const int* in_sizes, int n_in,
                              void* d_out, int out_size, void* d_ws, size_t ws_size,
                              hipStream_t stream) {
  const float* x    = (const float*)d_in[0];   // (b, l, d) fp32
  const float* filt = (const float*)d_in[1];   // (d, l) fp32
  float* y = (float*)d_out;                    // (b, l, d) fp32

  const int D = 1024, Lseq = 8192;
  const int B = in_sizes[0] / (D * Lseq);      // 4

  const size_t kf_bytes = (size_t)D * (M/2 + 1) * sizeof(float4);  // ~67 MB
  const float4* kf = nullptr;
  if (d_ws != nullptr && ws_size >= kf_bytes) {
    hipLaunchKernelGGL(filt_fft_kernel, dim3(D), dim3(NTH), 0, stream,
                       filt, (float4*)d_ws);
    kf = (const float4*)d_ws;
  }

  dim3 grid(B * D), block(NTH);
  hipLaunchKernelGGL(longconv_fft_kernel, grid, block, 0, stream, x, filt, kf, y, B);
}